// Round 7
// baseline (578.802 us; speedup 1.0000x reference)
//
#include <hip/hip_runtime.h>

// ---------------------------------------------------------------------------
// GCN graph classifier — bucketed CSR build + premultiplied bf16 gather table.
//   h1 = relu(gcnconv(x, W1, b1));  h2 = relu(gcnconv(h1, W2, b2));
//   g  = mean_pool(h2, batch);      out = g @ Wl + bl
// Factored norm with premul table: xws[s] = dis[s]*(x@W)[s]  (bf16)
//   out[i] = relu( dis[i] * (sum_{e->i} xws[src_e] + xws[i]) + b )
// CSR fill done in two passes (bucket-by-dst then LDS-place) so all global
// writes are sequential-frontier or 4KB-local — kills write-line thrash.
// ---------------------------------------------------------------------------

static __device__ inline ushort f32_to_bf16_rne(float f) {
    uint32_t u = __float_as_uint(f);
    uint32_t r = (u + 0x7fffu + ((u >> 16) & 1u)) >> 16;
    return (ushort)r;
}
static __device__ inline float bf_lo(uint32_t u) { return __uint_as_float(u << 16); }
static __device__ inline float bf_hi(uint32_t u) { return __uint_as_float(u & 0xffff0000u); }

// ---- degree histogram (int) ------------------------------------------------
__global__ __launch_bounds__(256) void deg_kernel(const int* __restrict__ col,
                                                  int* __restrict__ deg, int E) {
    int e = blockIdx.x * 256 + threadIdx.x;
    if (e < E) atomicAdd(&deg[col[e]], 1);
}

// ---- scan step 1: per-block sums (512 elems/block) -------------------------
__global__ __launch_bounds__(512) void block_sum_kernel(const int* __restrict__ deg,
                                                        int* __restrict__ bsums, int n) {
    __shared__ int sm[512];
    int i = blockIdx.x * 512 + threadIdx.x;
    sm[threadIdx.x] = (i < n) ? deg[i] : 0;
    __syncthreads();
    for (int s = 256; s > 0; s >>= 1) {
        if (threadIdx.x < s) sm[threadIdx.x] += sm[threadIdx.x + s];
        __syncthreads();
    }
    if (threadIdx.x == 0) bsums[blockIdx.x] = sm[0];
}

// ---- scan step 2: exclusive scan of block sums (nb <= 256, one block) ------
__global__ __launch_bounds__(256) void scan_bsums_kernel(int* __restrict__ bsums, int nb) {
    __shared__ int sm[256];
    int v = (threadIdx.x < nb) ? bsums[threadIdx.x] : 0;
    sm[threadIdx.x] = v;
    __syncthreads();
    for (int off = 1; off < 256; off <<= 1) {
        int t = (threadIdx.x >= off) ? sm[threadIdx.x - off] : 0;
        __syncthreads();
        sm[threadIdx.x] += t;
        __syncthreads();
    }
    if (threadIdx.x < nb) bsums[threadIdx.x] = sm[threadIdx.x] - v;  // exclusive
}

// ---- scan step 3: local scan + block offset -> row_ptr; also dis=rsqrt -----
__global__ __launch_bounds__(512) void scan_write_kernel(const int* __restrict__ deg,
                                                         const int* __restrict__ bsums,
                                                         int* __restrict__ rowptr,
                                                         float* __restrict__ dis,
                                                         int n, int E) {
    __shared__ int sm[512];
    int i = blockIdx.x * 512 + threadIdx.x;
    int v = (i < n) ? deg[i] : 0;
    sm[threadIdx.x] = v;
    __syncthreads();
    for (int off = 1; off < 512; off <<= 1) {
        int t = (threadIdx.x >= off) ? sm[threadIdx.x - off] : 0;
        __syncthreads();
        sm[threadIdx.x] += t;
        __syncthreads();
    }
    if (i < n) {
        rowptr[i] = bsums[blockIdx.x] + sm[threadIdx.x] - v;  // exclusive
        dis[i] = rsqrtf((float)v + 1.0f);                     // +1 = self loop
    }
    if (blockIdx.x == 0 && threadIdx.x == 0) rowptr[n] = E;
}

// ---- CSR fill pass 1: bucket edges by dst>>6, packed src|(dst&63)<<26 ------
// Writes advance a sequential frontier per bucket -> near-streaming.
__global__ __launch_bounds__(256) void bucket_pass1(const int* __restrict__ row,
                                                    const int* __restrict__ col,
                                                    const int* __restrict__ rowptr,
                                                    int* __restrict__ bfill,
                                                    int* __restrict__ inter, int E) {
    int e = blockIdx.x * 256 + threadIdx.x;
    if (e >= E) return;
    int r = row[e], c = col[e];
    int b = c >> 6;
    int base = rowptr[b << 6];
    int idx = atomicAdd(&bfill[b], 1);
    inter[base + idx] = r | ((c & 63) << 26);
}

// ---- CSR fill pass 2: one block per bucket; place within 4KB window --------
__global__ __launch_bounds__(256) void bucket_pass2(const int* __restrict__ inter,
                                                    const int* __restrict__ rowptr,
                                                    int* __restrict__ csrs, int n) {
    __shared__ int lcnt[64];
    const int nb0 = blockIdx.x << 6;
    const int nend = min(nb0 + 64, n);
    const int s = rowptr[nb0], t = rowptr[nend];
    if (threadIdx.x < 64) lcnt[threadIdx.x] = 0;
    __syncthreads();
    for (int e = s + threadIdx.x; e < t; e += 256) {
        int w = inter[e];
        int r = w & 0x03FFFFFF;
        int clow = (int)((unsigned)w >> 26);
        int pos = rowptr[nb0 + clow] + atomicAdd(&lcnt[clow], 1);
        csrs[pos] = r;
    }
}

// ---- register-tiled GEMM with dis-premul epilogue --------------------------
// out_bf16[node][64] = dis[node] * (x[node][K] @ W[K][64])
template <int K>
__global__ __launch_bounds__(256) void gemm_tiled(const float* __restrict__ x,
                                                  const float* __restrict__ W,
                                                  const float* __restrict__ dis,
                                                  ushort* __restrict__ out, int n) {
    __shared__ float As[32][68];     // [k][node], pad 68: float4-aligned rows,
    __shared__ float Ws[32 * 64];    //   spreads write banks {0..7,16..23}
    const int tid = threadIdx.x;
    const int tr = tid >> 4;         // 0..15 -> node quad
    const int tc = tid & 15;         // 0..15 -> out quad
    const int base = blockIdx.x * 64;

    float acc[4][4];
#pragma unroll
    for (int i = 0; i < 4; ++i)
#pragma unroll
        for (int j = 0; j < 4; ++j) acc[i][j] = 0.0f;

    const int tnode = tid >> 3;          // 0..31
    const int tk4 = (tid & 7) * 4;       // 0,4,...,28

    for (int kc = 0; kc < K; kc += 32) {
        __syncthreads();
#pragma unroll
        for (int h = 0; h < 2; ++h) {
            int m = tnode + h * 32;
            int node = base + m;
            float4 v = make_float4(0.f, 0.f, 0.f, 0.f);
            if (node < n) v = *(const float4*)&x[(size_t)node * K + kc + tk4];
            As[tk4 + 0][m] = v.x; As[tk4 + 1][m] = v.y;
            As[tk4 + 2][m] = v.z; As[tk4 + 3][m] = v.w;
        }
#pragma unroll
        for (int r = 0; r < 2; ++r) {
            int o = tid * 4 + r * 1024;
            *(float4*)&Ws[o] = *(const float4*)&W[kc * 64 + o];
        }
        __syncthreads();
#pragma unroll
        for (int k = 0; k < 32; ++k) {
            float4 a = *(const float4*)&As[k][tr * 4];
            float4 b = *(const float4*)&Ws[k * 64 + tc * 4];
            const float av[4] = {a.x, a.y, a.z, a.w};
            const float bv[4] = {b.x, b.y, b.z, b.w};
#pragma unroll
            for (int i = 0; i < 4; ++i)
#pragma unroll
                for (int j = 0; j < 4; ++j)
                    acc[i][j] = fmaf(av[i], bv[j], acc[i][j]);
        }
    }
#pragma unroll
    for (int i = 0; i < 4; ++i) {
        int node = base + tr * 4 + i;
        if (node < n) {
            float d = dis[node];
            ushort4 st;
            st.x = f32_to_bf16_rne(acc[i][0] * d);
            st.y = f32_to_bf16_rne(acc[i][1] * d);
            st.z = f32_to_bf16_rne(acc[i][2] * d);
            st.w = f32_to_bf16_rne(acc[i][3] * d);
            *(ushort4*)&out[(size_t)node * 64 + tc * 4] = st;
        }
    }
}

// ---- fused pull-aggregate + self-loop + bias + relu ------------------------
// half-wave per dst node (2 nodes/wave); 8-deep gather pipeline; adds only.
// out[i] = relu(dis[i]*(sum xws[src] + xws[i]) + b)
template <int OUT_BF16>
__global__ __launch_bounds__(256) void gcn_pull_kernel(const ushort* __restrict__ xws,
                                                       const int* __restrict__ csrs,
                                                       const int* __restrict__ rowptr,
                                                       const float* __restrict__ dis,
                                                       const float* __restrict__ b,
                                                       void* __restrict__ outv, int n) {
    const int lane = threadIdx.x & 63;
    const int wv = threadIdx.x >> 6;
    const int half = lane >> 5;          // which node of the pair
    const int q = lane & 31;             // feature pair index
    const float2 bb = ((const float2*)b)[q];

    const int i = (blockIdx.x * 4 + wv) * 2 + half;
    if (i >= n) return;

    const int s = rowptr[i], t = rowptr[i + 1];
    uint32_t us = *(const uint32_t*)(xws + ((size_t)i << 6) + (q << 1));
    float ax = bf_lo(us), ay = bf_hi(us);          // self loop (premul'd)
    int e = s;
    for (; e + 8 <= t; e += 8) {                   // 8 gathers in flight
        int s0 = csrs[e + 0], s1 = csrs[e + 1], s2 = csrs[e + 2], s3 = csrs[e + 3];
        int s4 = csrs[e + 4], s5 = csrs[e + 5], s6 = csrs[e + 6], s7 = csrs[e + 7];
        uint32_t u0 = *(const uint32_t*)(xws + ((size_t)s0 << 6) + (q << 1));
        uint32_t u1 = *(const uint32_t*)(xws + ((size_t)s1 << 6) + (q << 1));
        uint32_t u2 = *(const uint32_t*)(xws + ((size_t)s2 << 6) + (q << 1));
        uint32_t u3 = *(const uint32_t*)(xws + ((size_t)s3 << 6) + (q << 1));
        uint32_t u4 = *(const uint32_t*)(xws + ((size_t)s4 << 6) + (q << 1));
        uint32_t u5 = *(const uint32_t*)(xws + ((size_t)s5 << 6) + (q << 1));
        uint32_t u6 = *(const uint32_t*)(xws + ((size_t)s6 << 6) + (q << 1));
        uint32_t u7 = *(const uint32_t*)(xws + ((size_t)s7 << 6) + (q << 1));
        ax += bf_lo(u0); ay += bf_hi(u0);
        ax += bf_lo(u1); ay += bf_hi(u1);
        ax += bf_lo(u2); ay += bf_hi(u2);
        ax += bf_lo(u3); ay += bf_hi(u3);
        ax += bf_lo(u4); ay += bf_hi(u4);
        ax += bf_lo(u5); ay += bf_hi(u5);
        ax += bf_lo(u6); ay += bf_hi(u6);
        ax += bf_lo(u7); ay += bf_hi(u7);
    }
    for (; e + 2 <= t; e += 2) {
        int s0 = csrs[e], s1 = csrs[e + 1];
        uint32_t u0 = *(const uint32_t*)(xws + ((size_t)s0 << 6) + (q << 1));
        uint32_t u1 = *(const uint32_t*)(xws + ((size_t)s1 << 6) + (q << 1));
        ax += bf_lo(u0); ay += bf_hi(u0);
        ax += bf_lo(u1); ay += bf_hi(u1);
    }
    if (e < t) {
        int s0 = csrs[e];
        uint32_t u0 = *(const uint32_t*)(xws + ((size_t)s0 << 6) + (q << 1));
        ax += bf_lo(u0); ay += bf_hi(u0);
    }
    const float di = dis[i];
    float v0 = fmaxf(fmaf(di, ax, bb.x), 0.0f);
    float v1 = fmaxf(fmaf(di, ay, bb.y), 0.0f);
    if (OUT_BF16) {
        ushort2 st = make_ushort2(f32_to_bf16_rne(v0), f32_to_bf16_rne(v1));
        *(ushort2*)((ushort*)outv + ((size_t)i << 6) + (q << 1)) = st;
    } else {
        *(float2*)((float*)outv + ((size_t)i << 6) + (q << 1)) = make_float2(v0, v1);
    }
}

// ---- segmented mean-pool (batch sorted, bf16 input): 32 nodes/wave ---------
__global__ __launch_bounds__(256) void pool_kernel(const ushort* __restrict__ h,
                                                   const int* __restrict__ batch,
                                                   float* __restrict__ pool,
                                                   float* __restrict__ cnt, int n) {
    const int lane = threadIdx.x & 63;
    const int wid = threadIdx.x >> 6;
    const int start = (blockIdx.x * 4 + wid) * 32;
    const int end = min(start + 32, n);
    if (start >= end) return;
    int gcur = batch[start];
    float acc = 0.0f;
    int c = 0;
    for (int i = start; i < end; ++i) {
        int g = batch[i];           // wave-uniform
        if (g != gcur) {
            atomicAdd(&pool[gcur * 64 + lane], acc);
            if (lane == 0) atomicAdd(&cnt[gcur], (float)c);
            acc = 0.0f; c = 0; gcur = g;
        }
        acc += __uint_as_float((uint32_t)h[(size_t)i * 64 + lane] << 16);
        ++c;
    }
    atomicAdd(&pool[gcur * 64 + lane], acc);
    if (lane == 0) atomicAdd(&cnt[gcur], (float)c);
}

// ---- final: out[64][10] = (pool/cnt) @ Wl + bl -----------------------------
__global__ __launch_bounds__(640) void final_kernel(const float* __restrict__ pool,
                                                    const float* __restrict__ cnt,
                                                    const float* __restrict__ Wl,
                                                    const float* __restrict__ bl,
                                                    float* __restrict__ out) {
    int tid = threadIdx.x;            // 640 = 64 graphs * 10 outputs
    int g = tid / 10, o = tid % 10;
    float inv = 1.0f / fmaxf(cnt[g], 1.0f);
    float acc = 0.0f;
#pragma unroll
    for (int l = 0; l < 64; ++l)
        acc = fmaf(pool[g * 64 + l] * inv, Wl[l * 10 + o], acc);
    out[tid] = acc + bl[o];
}

extern "C" void kernel_launch(void* const* d_in, const int* in_sizes, int n_in,
                              void* d_out, int out_size, void* d_ws, size_t ws_size,
                              hipStream_t stream) {
    const float* x  = (const float*)d_in[0];
    const float* W1 = (const float*)d_in[1];
    const float* b1 = (const float*)d_in[2];
    const float* W2 = (const float*)d_in[3];
    const float* b2 = (const float*)d_in[4];
    const float* Wl = (const float*)d_in[5];
    const float* bl = (const float*)d_in[6];
    const int*   ei = (const int*)d_in[7];    // [2, E] -> row = ei, col = ei + E
    const int*   batch = (const int*)d_in[8];
    float* out = (float*)d_out;

    const int n = in_sizes[8];           // 100000 nodes
    const int E = in_sizes[7] / 2;       // 1600000 edges
    const int F = 64;

    const int* row = ei;
    const int* col = ei + E;

    // ---- workspace layout (256B-aligned chunks) ----
    char* p = (char*)d_ws;
    auto alloc = [&](size_t bytes) {
        char* r = p;
        p += (bytes + 255) & ~(size_t)255;
        return r;
    };
    int*    degi   = (int*)   alloc((size_t)n * 4);          // deg, reused as bfill
    int*    rowptr = (int*)   alloc((size_t)(n + 1) * 4);
    int*    bsums  = (int*)   alloc(256 * 4);
    float*  dis    = (float*) alloc((size_t)n * 4);
    int*    csrs   = (int*)   alloc((size_t)E * 4);          // src-only CSR
    int*    inter  = (int*)   alloc((size_t)E * 4);          // packed bucket pairs
    ushort* xwB    = (ushort*)alloc((size_t)n * F * 2);      // bf16 premul table
    float*  B      = (float*) alloc((size_t)n * F * 4);      // h1 f32 / h2 bf16 reuse
    float*  pool   = (float*) alloc(64 * 64 * 4);
    float*  cnt    = (float*) alloc(64 * 4);

    const int nb_edge = (E + 255) / 256;
    const int nb_scan = (n + 511) / 512;     // 196 for n=100000
    const int nb_gemm = (n + 63) / 64;       // 1563
    const int nbuck   = (n + 63) / 64;       // 64-node buckets

    // ---- CSR build ----
    hipMemsetAsync(degi, 0, (size_t)n * 4, stream);
    deg_kernel<<<nb_edge, 256, 0, stream>>>(col, degi, E);
    block_sum_kernel<<<nb_scan, 512, 0, stream>>>(degi, bsums, n);
    scan_bsums_kernel<<<1, 256, 0, stream>>>(bsums, nb_scan);
    scan_write_kernel<<<nb_scan, 512, 0, stream>>>(degi, bsums, rowptr, dis, n, E);
    hipMemsetAsync(degi, 0, (size_t)nbuck * 4, stream);      // reuse as bucket fill
    bucket_pass1<<<nb_edge, 256, 0, stream>>>(row, col, rowptr, degi, inter, E);
    bucket_pass2<<<nbuck, 256, 0, stream>>>(inter, rowptr, csrs, n);

    // ---- layer 1 ----
    gemm_tiled<128><<<nb_gemm, 256, 0, stream>>>(x, W1, dis, xwB, n);
    gcn_pull_kernel<0><<<(n + 7) / 8, 256, 0, stream>>>(xwB, csrs, rowptr, dis, b1, B, n);

    // ---- layer 2 ----
    gemm_tiled<64><<<nb_gemm, 256, 0, stream>>>(B, W2, dis, xwB, n);
    gcn_pull_kernel<1><<<(n + 7) / 8, 256, 0, stream>>>(xwB, csrs, rowptr, dis, b2, B, n);

    // ---- pool + classifier ----
    hipMemsetAsync(pool, 0, (64 * 64 + 64) * sizeof(float), stream);
    pool_kernel<<<(n + 127) / 128, 256, 0, stream>>>((const ushort*)B, batch, pool, cnt, n);
    final_kernel<<<1, 640, 0, stream>>>(pool, cnt, Wl, bl, out);
}